// Round 4
// baseline (4634.016 us; speedup 1.0000x reference)
//
#include <hip/hip_runtime.h>
#include <hip/hip_bf16.h>

// Bidirectional LSTM, B=32 T=512 D=H=512. f32 I/O, bf16 MFMA internally.
//
// R10: straggler-only polling + per-wave autonomous epilogue, grid=(32,2).
//  - Tagged 8B payload exchange (R9) kept; poll keeps an ok-bitmask and
//    reloads ONLY stale entries after the first sweep (sweep-1 IS the data
//    load). Poll LLC traffic ~ data volume instead of N_sweeps x 64KB.
//  - Sweep-1 issued BEFORE the x-MFMAs: its LLC RTT hides under compute.
//  - n-remap: wave owns 4 cols x 4 gates (n = cs*4 + gate). After MFMA a
//    4-lane shfl_xor transpose puts all 4 gates of one (batch,col) in one
//    lane -> cell fully in-wave, vbuf + barrier D deleted; each wave fires
//    its tagged h-store as soon as its own MFMAs finish.
//  - One barrier/step (C, lgkmcnt-only). hA parity-double-buffered (64KB)
//    so the single-barrier schedule has no LDS WAR race.
//  - Lane owns 4 consecutive entries per batch row -> hA staging is one
//    ds_write_b128 per batch.

typedef __bf16 bf16;
typedef __attribute__((ext_vector_type(8))) __bf16 bf16x8;
typedef __attribute__((ext_vector_type(4))) float f32x4;
typedef __attribute__((ext_vector_type(4))) unsigned u32x4;
typedef unsigned long long u64;

__device__ __forceinline__ float sigmoidf_(float x) {
  return 1.f / (1.f + __expf(-x));
}
__device__ __forceinline__ float tanhf_(float x) {
  float e = __expf(-2.f * fabsf(x));
  return copysignf((1.f - e) / (1.f + e), x);
}
__device__ __forceinline__ u64 ald64(const u64* p) {
  return __hip_atomic_load(p, __ATOMIC_RELAXED, __HIP_MEMORY_SCOPE_AGENT);
}
__device__ __forceinline__ void ast64(u64* p, u64 v) {
  __hip_atomic_store(p, v, __ATOMIC_RELAXED, __HIP_MEMORY_SCOPE_AGENT);
}
__device__ __forceinline__ bf16x8 cvt8v(float4 a, float4 b) {
  bf16x8 v;
  v[0] = (bf16)a.x; v[1] = (bf16)a.y; v[2] = (bf16)a.z; v[3] = (bf16)a.w;
  v[4] = (bf16)b.x; v[5] = (bf16)b.y; v[6] = (bf16)b.z; v[7] = (bf16)b.w;
  return v;
}
__device__ __forceinline__ void bar_lgkm() {
  asm volatile("s_waitcnt lgkmcnt(0)\n\ts_barrier" ::: "memory");
}
// 4x4 transpose within 4-lane groups: element (reg r, lane-sub g) -> (g, r).
__device__ __forceinline__ void tr4(f32x4& a, int lane) {
  const bool o1 = lane & 1, o2 = lane & 2;
  float ex;
  ex = __shfl_xor(o1 ? a[0] : a[1], 1); if (o1) a[0] = ex; else a[1] = ex;
  ex = __shfl_xor(o1 ? a[2] : a[3], 1); if (o1) a[2] = ex; else a[3] = ex;
  ex = __shfl_xor(o2 ? a[0] : a[2], 2); if (o2) a[0] = ex; else a[2] = ex;
  ex = __shfl_xor(o2 ? a[1] : a[3], 2); if (o2) a[1] = ex; else a[3] = ex;
}

// ---------------- lengths ----------------
__global__ void lengths_kernel(const int* __restrict__ mask, int* __restrict__ lengths) {
  __shared__ int part[32][8];
  int t = threadIdx.x;
  int b = t >> 3, sub = t & 7;
  int s = 0;
#pragma unroll 8
  for (int k = 0; k < 64; ++k) s += mask[b * 512 + sub + 8 * k];
  part[b][sub] = s;
  __syncthreads();
  if (sub == 0) {
    int tot = 0;
#pragma unroll
    for (int k = 0; k < 8; ++k) tot += part[b][k];
    lengths[b] = tot;
  }
}

// ---------------- fused persistent LSTM ----------------
__global__ __launch_bounds__(256, 1) void lstm_fused(
    const float* __restrict__ x,                                  // [32][512][512] f32
    const float* __restrict__ Wih_f, const float* __restrict__ bih_f,
    const float* __restrict__ Whh_f,
    const float* __restrict__ Wih_b, const float* __restrict__ bih_b,
    const float* __restrict__ Whh_b,
    const int* __restrict__ lengths,
    u64* __restrict__ hbuf,             // [2 dir][2 par][32 batch][256] u64 entries
    float* __restrict__ out) {          // [32][512][1024] f32
  const int s = blockIdx.x;             // h-col slice: cols [16s, 16s+16)
  const int dir = blockIdx.y;
  const float* Wih = dir ? Wih_b : Wih_f;
  const float* Whh = dir ? Whh_b : Whh_f;
  const float* bih = dir ? bih_b : bih_f;

  const int tid = threadIdx.x;
  const int lane = tid & 63, wave = tid >> 6;
  const int l15 = lane & 15, quad = lane >> 4;

  __shared__ __align__(16) bf16 xA[2][32 * 512];  // 2x32 KB x double buffer
  __shared__ __align__(16) bf16 hA[2][32 * 512];  // 2x32 KB h double buffer
  __shared__ int lenL[32];

  // n-map: n = l15 = cs*4 + gate; wave owns cols s*16 + wave*4 + cs.
  const int nG = l15 & 3;          // gate 0..3 = i,f,g,o
  const int nC = l15 >> 2;         // col-sub 0..3
  const int grow = nG * 512 + s * 16 + wave * 4 + nC;

  bf16x8 wih[16], whh[16];
#pragma unroll
  for (int k = 0; k < 16; ++k) {
    const float* pw = Wih + (size_t)grow * 512 + k * 32 + quad * 8;
    const float* ph = Whh + (size_t)grow * 512 + k * 32 + quad * 8;
    wih[k] = cvt8v(*(const float4*)pw, *(const float4*)(pw + 4));
    whh[k] = cvt8v(*(const float4*)ph, *(const float4*)(ph + 4));
  }
  const float bv = bih[grow];
  if (tid < 32) lenL[tid] = lengths[tid];
  __syncthreads();

  // per-lane output ownership (post-transpose): batch quad*4+(lane&3) (+16
  // for the acc1 half), col s*16 + wave*4 + cs.
  const int b3 = lane & 3;
  const bool hiCS = (lane & 4) != 0;            // cs odd
  const int bst = quad * 4 + b3 + (hiCS ? 16 : 0);  // batch this lane stores
  const int eIdx = s * 8 + wave * 2 + ((lane >> 3) & 1);
  const int colp = s * 16 + wave * 4 + ((lane >> 2) & 2);  // even col of pair
  int lenR[8];
#pragma unroll
  for (int i = 0; i < 8; ++i) lenR[i] = lenL[(i * 256 + tid) >> 6];
  const int lenS = lenL[bst];

  float creg0 = 0.f, creg1 = 0.f;
  u64* hb = hbuf + (size_t)dir * (2 * 32 * 256);

  // Prologue: load x(0), stage xA[0], then issue prefetch of x(1).
  float4 xp[8][2];
#pragma unroll
  for (int i = 0; i < 8; ++i) {
    int c = i * 256 + tid;
    int m = c >> 6, kbp = c & 63;
    int kb = kbp ^ (m & 7);
    int tr = (dir == 0) ? 0 : ((511 + lenR[i]) & 511);
    const float4* p = (const float4*)(x + ((size_t)m * 512 + tr) * 512 + kb * 8);
    xp[i][0] = p[0]; xp[i][1] = p[1];
  }
#pragma unroll
  for (int i = 0; i < 8; ++i) {
    int c = i * 256 + tid;
    *(bf16x8*)(xA[0] + c * 8) = cvt8v(xp[i][0], xp[i][1]);
  }
#pragma unroll
  for (int i = 0; i < 8; ++i) {
    int c = i * 256 + tid;
    int m = c >> 6, kbp = c & 63;
    int kb = kbp ^ (m & 7);
    int tr = (dir == 0) ? 1 : ((510 + lenR[i]) & 511);
    const float4* p = (const float4*)(x + ((size_t)m * 512 + tr) * 512 + kb * 8);
    xp[i][0] = p[0]; xp[i][1] = p[1];
  }
  bar_lgkm();  // xA[0] staged

  for (int step = 0; step < 512; ++step) {
    const int par = step & 1;
    const u64* hprev = hb + (size_t)par * (32 * 256);
    u64* hnext = hb + (size_t)(par ^ 1) * (32 * 256);
    const bf16* xcur = xA[par];
    bf16* xnxt = xA[par ^ 1];
    bf16* hAc = hA[par];

    // ---- (1) sweep-1 h loads: issue EARLY, RTT hides under window+MFMA ----
    // wave w covers batches [8w,8w+8); lane owns entries [4*lane, 4*lane+4).
    u64 hv[8][4];
#pragma unroll
    for (int b = 0; b < 8; ++b) {
      const u64* rp = hprev + (wave * 8 + b) * 256 + 4 * lane;
#pragma unroll
      for (int j = 0; j < 4; ++j) hv[b][j] = ald64(rp + j);
    }
    __builtin_amdgcn_sched_barrier(0);  // loads first

    // ---- (2) window work: xA(t+1) stage from regs, x(t+2) prefetch ----
    if (step < 511) {
#pragma unroll
      for (int i = 0; i < 8; ++i) {
        int c = i * 256 + tid;
        *(bf16x8*)(xnxt + c * 8) = cvt8v(xp[i][0], xp[i][1]);
      }
    }
    if (step < 510) {
#pragma unroll
      for (int i = 0; i < 8; ++i) {
        int c = i * 256 + tid;
        int m = c >> 6, kbp = c & 63;
        int kb = kbp ^ (m & 7);
        int tr = (dir == 0) ? (step + 2) : ((509 - step + lenR[i]) & 511);
        const float4* p = (const float4*)(x + ((size_t)m * 512 + tr) * 512 + kb * 8);
        xp[i][0] = p[0]; xp[i][1] = p[1];
      }
    }

    // ---- (3) x-part MFMAs: v += x@Wih^T (+bias) ----
    f32x4 acc0 = {bv, bv, bv, bv};
    f32x4 acc1 = {bv, bv, bv, bv};
#pragma unroll
    for (int k = 0; k < 16; ++k) {
      int kb = k * 4 + quad;
      int sw = (kb ^ (l15 & 7)) * 8;
      bf16x8 ax0 = *(const bf16x8*)(xcur + l15 * 512 + sw);
      bf16x8 ax1 = *(const bf16x8*)(xcur + (16 + l15) * 512 + sw);
      acc0 = __builtin_amdgcn_mfma_f32_16x16x32_bf16(ax0, wih[k], acc0, 0, 0, 0);
      acc1 = __builtin_amdgcn_mfma_f32_16x16x32_bf16(ax1, wih[k], acc1, 0, 0, 0);
    }
    __builtin_amdgcn_sched_barrier(0);  // keep tag-check (vmcnt waits) below

    // ---- (4) tag check + straggler-only re-poll ----
    const unsigned target = (unsigned)step;
    unsigned okm = 0;
#pragma unroll
    for (int b = 0; b < 8; ++b)
#pragma unroll
      for (int j = 0; j < 4; ++j)
        okm |= (((unsigned)(hv[b][j] >> 32) >= target) ? 1u : 0u) << (b * 4 + j);
    bool done = __all((int)(okm == 0xffffffffu));
    while (!done) {
#pragma unroll
      for (int b = 0; b < 8; ++b)
#pragma unroll
        for (int j = 0; j < 4; ++j) {
          unsigned bit = 1u << (b * 4 + j);
          if (!(okm & bit)) {
            u64 v = ald64(hprev + (wave * 8 + b) * 256 + 4 * lane + j);
            if ((unsigned)(v >> 32) >= target) { hv[b][j] = v; okm |= bit; }
          }
        }
      done = __all((int)(okm == 0xffffffffu));
      if (!done) __builtin_amdgcn_s_sleep(1);
    }

    // ---- (5) stage payloads -> swizzled hA[par] (one b128 per batch) ----
#pragma unroll
    for (int b = 0; b < 8; ++b) {
      int m = wave * 8 + b;
      u32x4 blk = {(unsigned)hv[b][0], (unsigned)hv[b][1],
                   (unsigned)hv[b][2], (unsigned)hv[b][3]};
      *(u32x4*)(hAc + m * 512 + ((lane ^ (m & 7)) * 8)) = blk;
    }
    bar_lgkm();  // C: hA[par] + xnxt visible (the only barrier per step)

    // ---- (6) h-part MFMAs: v += h@Whh^T ----
#pragma unroll
    for (int k = 0; k < 16; ++k) {
      int kb = k * 4 + quad;
      int sw = (kb ^ (l15 & 7)) * 8;
      bf16x8 ah0 = *(const bf16x8*)(hAc + l15 * 512 + sw);
      bf16x8 ah1 = *(const bf16x8*)(hAc + (16 + l15) * 512 + sw);
      acc0 = __builtin_amdgcn_mfma_f32_16x16x32_bf16(ah0, whh[k], acc0, 0, 0, 0);
      acc1 = __builtin_amdgcn_mfma_f32_16x16x32_bf16(ah1, whh[k], acc1, 0, 0, 0);
    }

    // ---- (7) in-wave gate transpose + cell (no vbuf, no barrier D) ----
    tr4(acc0, lane);   // now acc[gate] for (batch quad*4+b3, col colbase+cs)
    tr4(acc1, lane);   // same for batch +16
    float c0 = sigmoidf_(acc0[1]) * creg0 + sigmoidf_(acc0[0]) * tanhf_(acc0[2]);
    float c1 = sigmoidf_(acc1[1]) * creg1 + sigmoidf_(acc1[0]) * tanhf_(acc1[2]);
    creg0 = c0; creg1 = c1;
    float h0 = tanhf_(c0) * sigmoidf_(acc0[3]);
    float h1 = tanhf_(c1) * sigmoidf_(acc1[3]);

    // ---- (8) tagged h store: pair adjacent cols via shfl_xor(4) ----
    unsigned u0 = (unsigned)__builtin_bit_cast(unsigned short, (bf16)h0);
    unsigned u1 = (unsigned)__builtin_bit_cast(unsigned short, (bf16)h1);
    unsigned pu0 = __shfl_xor(u0, 4), pu1 = __shfl_xor(u1, 4);
    unsigned payload = hiCS ? (pu1 | (u1 << 16)) : (u0 | (pu0 << 16));
    u64 pk = ((u64)(unsigned)(step + 1) << 32) | (u64)payload;
    ast64(hnext + bst * 256 + eIdx, pk);   // fire and forget

    // ---- (9) out store (f32 pair, after the data "signal") ----
    float ph0 = __shfl_xor(h0, 4), ph1 = __shfl_xor(h1, 4);
    float2 ov = hiCS ? make_float2(ph1, h1) : make_float2(h0, ph0);
    int tr = (dir == 0) ? step : ((511 - step + lenS) & 511);
    *(float2*)(out + (size_t)(bst * 512 + tr) * 1024 + dir * 512 + colp) = ov;
  }
}

extern "C" void kernel_launch(void* const* d_in, const int* in_sizes, int n_in,
                              void* d_out, int out_size, void* d_ws, size_t ws_size,
                              hipStream_t stream) {
  (void)in_sizes; (void)n_in; (void)out_size; (void)ws_size;
  const float* x    = (const float*)d_in[0];
  const int*   mask = (const int*)  d_in[1];
  const float* Wihf = (const float*)d_in[2];
  const float* bihf = (const float*)d_in[3];
  const float* Whhf = (const float*)d_in[4];
  const float* Wihb = (const float*)d_in[5];
  const float* bihb = (const float*)d_in[6];
  const float* Whhb = (const float*)d_in[7];
  float* out = (float*)d_out;

  char* ws = (char*)d_ws;
  u64* hbuf = (u64*)ws;                          // 2*2*32*256*8 = 262144 B
  int* lengths = (int*)(ws + 262144);            // 128 B
  const size_t head = 262144;

  hipMemsetAsync(d_ws, 0, head, stream);  // zero tags + h0 = c0 = 0 every call
  lengths_kernel<<<1, 256, 0, stream>>>(mask, lengths);
  lstm_fused<<<dim3(32, 2), 256, 0, stream>>>(
      x, Wihf, bihf, Whhf, Wihb, bihb, Whhb, lengths, hbuf, out);
}

// Round 5
// 2809.338 us; speedup vs baseline: 1.6495x; 1.6495x over previous
//
#include <hip/hip_runtime.h>
#include <hip/hip_bf16.h>

// Bidirectional LSTM, B=32 T=512 D=H=512. f32 I/O, bf16 MFMA internally.
//
// R11 = R9 poll discipline + R10 epilogue, liveness-managed.
//  - Tagged 8B payload exchange (R9). Poll = full batched re-sweep: all 32
//    loads issued unconditionally, ONE vmcnt wait, check, s_sleep, repeat.
//    (R10's straggler-only masked loads serialized under divergence.)
//  - Sweep-1 issued BEFORE x-MFMAs (RTT hides under compute). Register
//    liveness: xp staged to LDS first (xp dies) -> sweep (hv live across
//    x-MFMAs only) -> hA stage (hv dies) -> xp reload. Peak ~160 live.
//  - Per-wave epilogue kept: in-wave tr4 gate transpose, no vbuf, no
//    barrier D; wave fires its tagged h-store right after its cell.
//  - hA SINGLE buffer: safe because a wg's own h(t+1) store follows its
//    hA(t) reads in program order, and the consumer's poll(t+1) certifies
//    those stores -> staging writes(t+1) cannot race reads(t).
//  - One barrier/step (C, lgkmcnt-only; x prefetch rides through).

typedef __bf16 bf16;
typedef __attribute__((ext_vector_type(8))) __bf16 bf16x8;
typedef __attribute__((ext_vector_type(4))) float f32x4;
typedef __attribute__((ext_vector_type(4))) unsigned u32x4;
typedef unsigned long long u64;

__device__ __forceinline__ float sigmoidf_(float x) {
  return 1.f / (1.f + __expf(-x));
}
__device__ __forceinline__ float tanhf_(float x) {
  float e = __expf(-2.f * fabsf(x));
  return copysignf((1.f - e) / (1.f + e), x);
}
__device__ __forceinline__ u64 ald64(const u64* p) {
  return __hip_atomic_load(p, __ATOMIC_RELAXED, __HIP_MEMORY_SCOPE_AGENT);
}
__device__ __forceinline__ void ast64(u64* p, u64 v) {
  __hip_atomic_store(p, v, __ATOMIC_RELAXED, __HIP_MEMORY_SCOPE_AGENT);
}
__device__ __forceinline__ bf16x8 cvt8v(float4 a, float4 b) {
  bf16x8 v;
  v[0] = (bf16)a.x; v[1] = (bf16)a.y; v[2] = (bf16)a.z; v[3] = (bf16)a.w;
  v[4] = (bf16)b.x; v[5] = (bf16)b.y; v[6] = (bf16)b.z; v[7] = (bf16)b.w;
  return v;
}
__device__ __forceinline__ void bar_lgkm() {
  asm volatile("s_waitcnt lgkmcnt(0)\n\ts_barrier" ::: "memory");
}
// 4x4 transpose within 4-lane groups: element (reg r, lane-sub g) -> (g, r).
__device__ __forceinline__ void tr4(f32x4& a, int lane) {
  const bool o1 = lane & 1, o2 = lane & 2;
  float ex;
  ex = __shfl_xor(o1 ? a[0] : a[1], 1); if (o1) a[0] = ex; else a[1] = ex;
  ex = __shfl_xor(o1 ? a[2] : a[3], 1); if (o1) a[2] = ex; else a[3] = ex;
  ex = __shfl_xor(o2 ? a[0] : a[2], 2); if (o2) a[0] = ex; else a[2] = ex;
  ex = __shfl_xor(o2 ? a[1] : a[3], 2); if (o2) a[1] = ex; else a[3] = ex;
}

// ---------------- lengths ----------------
__global__ void lengths_kernel(const int* __restrict__ mask, int* __restrict__ lengths) {
  __shared__ int part[32][8];
  int t = threadIdx.x;
  int b = t >> 3, sub = t & 7;
  int s = 0;
#pragma unroll 8
  for (int k = 0; k < 64; ++k) s += mask[b * 512 + sub + 8 * k];
  part[b][sub] = s;
  __syncthreads();
  if (sub == 0) {
    int tot = 0;
#pragma unroll
    for (int k = 0; k < 8; ++k) tot += part[b][k];
    lengths[b] = tot;
  }
}

// ---------------- fused persistent LSTM ----------------
__global__ __launch_bounds__(256, 1) void lstm_fused(
    const float* __restrict__ x,                                  // [32][512][512] f32
    const float* __restrict__ Wih_f, const float* __restrict__ bih_f,
    const float* __restrict__ Whh_f,
    const float* __restrict__ Wih_b, const float* __restrict__ bih_b,
    const float* __restrict__ Whh_b,
    const int* __restrict__ lengths,
    u64* __restrict__ hbuf,             // [2 dir][2 par][32 batch][256] u64 entries
    float* __restrict__ out) {          // [32][512][1024] f32
  const int s = blockIdx.x;             // h-col slice: cols [16s, 16s+16)
  const int dir = blockIdx.y;
  const float* Wih = dir ? Wih_b : Wih_f;
  const float* Whh = dir ? Whh_b : Whh_f;
  const float* bih = dir ? bih_b : bih_f;

  const int tid = threadIdx.x;
  const int lane = tid & 63, wave = tid >> 6;
  const int l15 = lane & 15, quad = lane >> 4;

  __shared__ __align__(16) bf16 xA[2][32 * 512];  // 2x32 KB x double buffer
  __shared__ __align__(16) bf16 hA[32 * 512];     // 32 KB h (single; see proof)
  __shared__ int lenL[32];

  // n-map: n = l15 = cs*4 + gate; wave owns cols s*16 + wave*4 + cs.
  const int nG = l15 & 3;          // gate 0..3 = i,f,g,o
  const int nC = l15 >> 2;         // col-sub 0..3
  const int grow = nG * 512 + s * 16 + wave * 4 + nC;

  bf16x8 wih[16], whh[16];
#pragma unroll
  for (int k = 0; k < 16; ++k) {
    const float* pw = Wih + (size_t)grow * 512 + k * 32 + quad * 8;
    const float* ph = Whh + (size_t)grow * 512 + k * 32 + quad * 8;
    wih[k] = cvt8v(*(const float4*)pw, *(const float4*)(pw + 4));
    whh[k] = cvt8v(*(const float4*)ph, *(const float4*)(ph + 4));
  }
  const float bv = bih[grow];
  if (tid < 32) lenL[tid] = lengths[tid];
  __syncthreads();

  // per-lane output ownership (post-transpose): batch quad*4+(lane&3) (+16
  // for the acc1 half), col s*16 + wave*4 + cs.
  const int b3 = lane & 3;
  const bool hiCS = (lane & 4) != 0;                 // cs odd
  const int bst = quad * 4 + b3 + (hiCS ? 16 : 0);   // batch this lane stores
  const int eIdx = s * 8 + wave * 2 + ((lane >> 3) & 1);
  const int colp = s * 16 + wave * 4 + ((lane >> 2) & 2);  // even col of pair
  int lenR[8];
#pragma unroll
  for (int i = 0; i < 8; ++i) lenR[i] = lenL[(i * 256 + tid) >> 6];
  const int lenS = lenL[bst];

  float creg0 = 0.f, creg1 = 0.f;
  u64* hb = hbuf + (size_t)dir * (2 * 32 * 256);

  // Prologue: load x(0), stage xA[0], then issue prefetch of x(1).
  float4 xp[8][2];
#pragma unroll
  for (int i = 0; i < 8; ++i) {
    int c = i * 256 + tid;
    int m = c >> 6, kbp = c & 63;
    int kb = kbp ^ (m & 7);
    int tr = (dir == 0) ? 0 : ((511 + lenR[i]) & 511);
    const float4* p = (const float4*)(x + ((size_t)m * 512 + tr) * 512 + kb * 8);
    xp[i][0] = p[0]; xp[i][1] = p[1];
  }
#pragma unroll
  for (int i = 0; i < 8; ++i) {
    int c = i * 256 + tid;
    *(bf16x8*)(xA[0] + c * 8) = cvt8v(xp[i][0], xp[i][1]);
  }
#pragma unroll
  for (int i = 0; i < 8; ++i) {
    int c = i * 256 + tid;
    int m = c >> 6, kbp = c & 63;
    int kb = kbp ^ (m & 7);
    int tr = (dir == 0) ? 1 : ((510 + lenR[i]) & 511);
    const float4* p = (const float4*)(x + ((size_t)m * 512 + tr) * 512 + kb * 8);
    xp[i][0] = p[0]; xp[i][1] = p[1];
  }
  bar_lgkm();  // xA[0] staged

  for (int step = 0; step < 512; ++step) {
    const int par = step & 1;
    const u64* hprev = hb + (size_t)par * (32 * 256);
    u64* hnext = hb + (size_t)(par ^ 1) * (32 * 256);
    const bf16* xcur = xA[par];
    bf16* xnxt = xA[par ^ 1];

    // ---- (1) stage xA(t+1) from regs (xp dies here) ----
    if (step < 511) {
#pragma unroll
      for (int i = 0; i < 8; ++i) {
        int c = i * 256 + tid;
        *(bf16x8*)(xnxt + c * 8) = cvt8v(xp[i][0], xp[i][1]);
      }
    }

    // ---- (2) sweep-1 h loads (hv live from here to (5)) ----
    // wave w covers batches [8w,8w+8); lane owns entries [4*lane, 4*lane+4).
    u64 hv[8][4];
#pragma unroll
    for (int b = 0; b < 8; ++b) {
      const u64* rp = hprev + (wave * 8 + b) * 256 + 4 * lane;
#pragma unroll
      for (int j = 0; j < 4; ++j) hv[b][j] = ald64(rp + j);
    }
    __builtin_amdgcn_sched_barrier(0);  // sweep issued before MFMA section

    // ---- (3) x-part MFMAs: v = x@Wih^T + bias ----
    f32x4 acc0 = {bv, bv, bv, bv};
    f32x4 acc1 = {bv, bv, bv, bv};
#pragma unroll
    for (int k = 0; k < 16; ++k) {
      int kb = k * 4 + quad;
      int sw = (kb ^ (l15 & 7)) * 8;
      bf16x8 ax0 = *(const bf16x8*)(xcur + l15 * 512 + sw);
      bf16x8 ax1 = *(const bf16x8*)(xcur + (16 + l15) * 512 + sw);
      acc0 = __builtin_amdgcn_mfma_f32_16x16x32_bf16(ax0, wih[k], acc0, 0, 0, 0);
      acc1 = __builtin_amdgcn_mfma_f32_16x16x32_bf16(ax1, wih[k], acc1, 0, 0, 0);
    }
    __builtin_amdgcn_sched_barrier(0);

    // ---- (4) tag check + DENSE batched re-sweeps (no masked loads) ----
    {
      const unsigned target = (unsigned)step;
      while (true) {
        int ok = 1;
#pragma unroll
        for (int b = 0; b < 8; ++b)
#pragma unroll
          for (int j = 0; j < 4; ++j)
            ok &= (int)((unsigned)(hv[b][j] >> 32) >= target);
        if (__all(ok)) break;
        __builtin_amdgcn_s_sleep(1);
#pragma unroll
        for (int b = 0; b < 8; ++b) {
          const u64* rp = hprev + (wave * 8 + b) * 256 + 4 * lane;
#pragma unroll
          for (int j = 0; j < 4; ++j) hv[b][j] = ald64(rp + j);
        }
      }
    }

    // ---- (5) stage payloads -> swizzled hA (one b128 per batch; hv dies) ----
#pragma unroll
    for (int b = 0; b < 8; ++b) {
      int m = wave * 8 + b;
      u32x4 blk = {(unsigned)hv[b][0], (unsigned)hv[b][1],
                   (unsigned)hv[b][2], (unsigned)hv[b][3]};
      *(u32x4*)(hA + m * 512 + ((lane ^ (m & 7)) * 8)) = blk;
    }

    // ---- (6) x(t+2) prefetch reload (xp live again) ----
    if (step < 510) {
#pragma unroll
      for (int i = 0; i < 8; ++i) {
        int c = i * 256 + tid;
        int m = c >> 6, kbp = c & 63;
        int kb = kbp ^ (m & 7);
        int tr = (dir == 0) ? (step + 2) : ((509 - step + lenR[i]) & 511);
        const float4* p = (const float4*)(x + ((size_t)m * 512 + tr) * 512 + kb * 8);
        xp[i][0] = p[0]; xp[i][1] = p[1];
      }
    }
    bar_lgkm();  // C: hA + xnxt visible (the only barrier per step)

    // ---- (7) h-part MFMAs: v += h@Whh^T ----
#pragma unroll
    for (int k = 0; k < 16; ++k) {
      int kb = k * 4 + quad;
      int sw = (kb ^ (l15 & 7)) * 8;
      bf16x8 ah0 = *(const bf16x8*)(hA + l15 * 512 + sw);
      bf16x8 ah1 = *(const bf16x8*)(hA + (16 + l15) * 512 + sw);
      acc0 = __builtin_amdgcn_mfma_f32_16x16x32_bf16(ah0, whh[k], acc0, 0, 0, 0);
      acc1 = __builtin_amdgcn_mfma_f32_16x16x32_bf16(ah1, whh[k], acc1, 0, 0, 0);
    }

    // ---- (8) in-wave gate transpose + cell (no vbuf, no barrier D) ----
    tr4(acc0, lane);   // acc[gate] for (batch quad*4+b3, col base+cs)
    tr4(acc1, lane);   // same for batch +16
    float c0 = sigmoidf_(acc0[1]) * creg0 + sigmoidf_(acc0[0]) * tanhf_(acc0[2]);
    float c1 = sigmoidf_(acc1[1]) * creg1 + sigmoidf_(acc1[0]) * tanhf_(acc1[2]);
    creg0 = c0; creg1 = c1;
    float h0 = tanhf_(c0) * sigmoidf_(acc0[3]);
    float h1 = tanhf_(c1) * sigmoidf_(acc1[3]);

    // ---- (9) tagged h store: pair adjacent cols via shfl_xor(4) ----
    unsigned u0 = (unsigned)__builtin_bit_cast(unsigned short, (bf16)h0);
    unsigned u1 = (unsigned)__builtin_bit_cast(unsigned short, (bf16)h1);
    unsigned pu0 = __shfl_xor(u0, 4), pu1 = __shfl_xor(u1, 4);
    unsigned payload = hiCS ? (pu1 | (u1 << 16)) : (u0 | (pu0 << 16));
    u64 pk = ((u64)(unsigned)(step + 1) << 32) | (u64)payload;
    ast64(hnext + bst * 256 + eIdx, pk);   // fire and forget

    // ---- (10) out store (after the data "signal") ----
    float ph0 = __shfl_xor(h0, 4), ph1 = __shfl_xor(h1, 4);
    float2 ov = hiCS ? make_float2(ph1, h1) : make_float2(h0, ph0);
    int tr = (dir == 0) ? step : ((511 - step + lenS) & 511);
    *(float2*)(out + (size_t)(bst * 512 + tr) * 1024 + dir * 512 + colp) = ov;
  }
}

extern "C" void kernel_launch(void* const* d_in, const int* in_sizes, int n_in,
                              void* d_out, int out_size, void* d_ws, size_t ws_size,
                              hipStream_t stream) {
  (void)in_sizes; (void)n_in; (void)out_size; (void)ws_size;
  const float* x    = (const float*)d_in[0];
  const int*   mask = (const int*)  d_in[1];
  const float* Wihf = (const float*)d_in[2];
  const float* bihf = (const float*)d_in[3];
  const float* Whhf = (const float*)d_in[4];
  const float* Wihb = (const float*)d_in[5];
  const float* bihb = (const float*)d_in[6];
  const float* Whhb = (const float*)d_in[7];
  float* out = (float*)d_out;

  char* ws = (char*)d_ws;
  u64* hbuf = (u64*)ws;                          // 2*2*32*256*8 = 262144 B
  int* lengths = (int*)(ws + 262144);            // 128 B
  const size_t head = 262144;

  hipMemsetAsync(d_ws, 0, head, stream);  // zero tags + h0 = c0 = 0 every call
  lengths_kernel<<<1, 256, 0, stream>>>(mask, lengths);
  lstm_fused<<<dim3(32, 2), 256, 0, stream>>>(
      x, Wihf, bihf, Whhf, Wihb, bihb, Whhb, lengths, hbuf, out);
}

// Round 6
// 2636.267 us; speedup vs baseline: 1.7578x; 1.0656x over previous
//
#include <hip/hip_runtime.h>
#include <hip/hip_bf16.h>

// Bidirectional LSTM, B=32 T=512 D=H=512. f32 I/O, bf16 MFMA internally.
//
// R12 = R9's exchange fabric + epilogue (the 2110us config), with R11's
//       consumer-side load ordering only.
//  - Exchange identical to R9: wave=gate mapping, vbuf + barrier D, h-store
//    = one coalesced 64B line per 8 lanes of ONE wave (entry s*8+(tid&7),
//    batch cb=tid>>3), coalesced out-store. (R10/R11's per-wave epilogue
//    scattered each 64B exchange line across 4 waves x 16B partial writes
//    -> LLC partial-line serialization + max-of-4-waves tag completion;
//    WRITE_SIZE 131->196MB and +640us. Reverted.)
//  - Kept from R11 (consumer-local):
//    (1) sweep-1 issued BEFORE x-MFMAs: poll RTT hides under staging+MFMA,
//        and the tag-check's vmcnt(0) covers ONLY sweep loads.
//    (2) x(t+2) prefetch issued AFTER detect (never inside a poll wait;
//        ~2us of slack before its consumer next step).
//    (3) hA staging = one ds_write_b128 per batch (lane owns 4 consecutive
//        entries = 8 cols).
//  - Tagged 8B payload exchange (R9): tag=step+1 in high dword; poll = full
//    dense batched re-sweep (32 loads, one wait, check, s_sleep, repeat).
//  - 2 lgkm-only barriers/step (C: hA/xA visible, D: vbuf).

typedef __bf16 bf16;
typedef __attribute__((ext_vector_type(8))) __bf16 bf16x8;
typedef __attribute__((ext_vector_type(4))) float f32x4;
typedef __attribute__((ext_vector_type(4))) unsigned u32x4;
typedef unsigned long long u64;

__device__ __forceinline__ float sigmoidf_(float x) {
  return 1.f / (1.f + __expf(-x));
}
__device__ __forceinline__ float tanhf_(float x) {
  float e = __expf(-2.f * fabsf(x));
  return copysignf((1.f - e) / (1.f + e), x);
}
__device__ __forceinline__ u64 ald64(const u64* p) {
  return __hip_atomic_load(p, __ATOMIC_RELAXED, __HIP_MEMORY_SCOPE_AGENT);
}
__device__ __forceinline__ void ast64(u64* p, u64 v) {
  __hip_atomic_store(p, v, __ATOMIC_RELAXED, __HIP_MEMORY_SCOPE_AGENT);
}
__device__ __forceinline__ bf16x8 cvt8v(float4 a, float4 b) {
  bf16x8 v;
  v[0] = (bf16)a.x; v[1] = (bf16)a.y; v[2] = (bf16)a.z; v[3] = (bf16)a.w;
  v[4] = (bf16)b.x; v[5] = (bf16)b.y; v[6] = (bf16)b.z; v[7] = (bf16)b.w;
  return v;
}
// Barrier with LDS-visibility only: does NOT drain vmcnt, so in-flight
// global loads survive across it.
__device__ __forceinline__ void bar_lgkm() {
  asm volatile("s_waitcnt lgkmcnt(0)\n\ts_barrier" ::: "memory");
}

// ---------------- lengths ----------------
__global__ void lengths_kernel(const int* __restrict__ mask, int* __restrict__ lengths) {
  __shared__ int part[32][8];
  int t = threadIdx.x;
  int b = t >> 3, sub = t & 7;
  int s = 0;
#pragma unroll 8
  for (int k = 0; k < 64; ++k) s += mask[b * 512 + sub + 8 * k];
  part[b][sub] = s;
  __syncthreads();
  if (sub == 0) {
    int tot = 0;
#pragma unroll
    for (int k = 0; k < 8; ++k) tot += part[b][k];
    lengths[b] = tot;
  }
}

// ---------------- fused persistent LSTM ----------------
__global__ __launch_bounds__(256, 1) void lstm_fused(
    const float* __restrict__ x,                                  // [32][512][512] f32
    const float* __restrict__ Wih_f, const float* __restrict__ bih_f,
    const float* __restrict__ Whh_f,
    const float* __restrict__ Wih_b, const float* __restrict__ bih_b,
    const float* __restrict__ Whh_b,
    const int* __restrict__ lengths,
    u64* __restrict__ hbuf,             // [2 dir][2 par][32 batch][256] u64 entries
    float* __restrict__ out) {          // [32][512][1024] f32
  const int s = blockIdx.x;             // h-col slice: cols [16s, 16s+16)
  const int dir = blockIdx.y;
  const float* Wih = dir ? Wih_b : Wih_f;
  const float* Whh = dir ? Whh_b : Whh_f;
  const float* bih = dir ? bih_b : bih_f;

  const int tid = threadIdx.x;
  const int lane = tid & 63, wave = tid >> 6;
  const int l15 = lane & 15, quad = lane >> 4;

  __shared__ __align__(16) bf16 xA[2][32 * 512];  // 2x32 KB x double buffer
  __shared__ __align__(16) bf16 hA[32 * 512];     // 32 KB h (single)
  __shared__ float vbuf[4][32][17];
  __shared__ int lenL[32];

  // Weight slices f32 -> bf16 registers (wave = gate; B-frag n=l15).
  bf16x8 wih[16], whh[16];
  {
    int grow = wave * 512 + s * 16 + l15;
#pragma unroll
    for (int k = 0; k < 16; ++k) {
      const float* pw = Wih + (size_t)grow * 512 + k * 32 + quad * 8;
      const float* ph = Whh + (size_t)grow * 512 + k * 32 + quad * 8;
      wih[k] = cvt8v(*(const float4*)pw, *(const float4*)(pw + 4));
      whh[k] = cvt8v(*(const float4*)ph, *(const float4*)(ph + 4));
    }
  }
  const float bv = bih[wave * 512 + s * 16 + l15];
  if (tid < 32) lenL[tid] = lengths[tid];
  __syncthreads();

  const int cb = tid >> 3, cj = (tid & 7) * 2;
  int lenR[8];
#pragma unroll
  for (int i = 0; i < 8; ++i) lenR[i] = lenL[(i * 256 + tid) >> 6];
  const int lenO = lenL[cb];

  float creg0 = 0.f, creg1 = 0.f;
  u64* hb = hbuf + (size_t)dir * (2 * 32 * 256);

  // Prologue: load x(0), stage xA[0], then issue prefetch of x(1).
  float4 xp[8][2];
#pragma unroll
  for (int i = 0; i < 8; ++i) {
    int c = i * 256 + tid;
    int m = c >> 6, kbp = c & 63;
    int kb = kbp ^ (m & 7);
    int tr = (dir == 0) ? 0 : ((511 + lenR[i]) & 511);
    const float4* p = (const float4*)(x + ((size_t)m * 512 + tr) * 512 + kb * 8);
    xp[i][0] = p[0]; xp[i][1] = p[1];
  }
#pragma unroll
  for (int i = 0; i < 8; ++i) {
    int c = i * 256 + tid;
    *(bf16x8*)(xA[0] + c * 8) = cvt8v(xp[i][0], xp[i][1]);
  }
#pragma unroll
  for (int i = 0; i < 8; ++i) {
    int c = i * 256 + tid;
    int m = c >> 6, kbp = c & 63;
    int kb = kbp ^ (m & 7);
    int tr = (dir == 0) ? 1 : ((510 + lenR[i]) & 511);
    const float4* p = (const float4*)(x + ((size_t)m * 512 + tr) * 512 + kb * 8);
    xp[i][0] = p[0]; xp[i][1] = p[1];
  }
  bar_lgkm();  // xA[0] staged

  for (int step = 0; step < 512; ++step) {
    const int par = step & 1;
    const u64* hprev = hb + (size_t)par * (32 * 256);
    u64* hnext = hb + (size_t)(par ^ 1) * (32 * 256);
    const bf16* xcur = xA[par];
    bf16* xnxt = xA[par ^ 1];

    // ---- (1) stage xA(t+1) from regs (LDS writes; xp dies) ----
    if (step < 511) {
#pragma unroll
      for (int i = 0; i < 8; ++i) {
        int c = i * 256 + tid;
        *(bf16x8*)(xnxt + c * 8) = cvt8v(xp[i][0], xp[i][1]);
      }
    }

    // ---- (2) sweep-1 h loads: only outstanding vmem at the tag check ----
    // wave w covers batches [8w,8w+8); lane owns entries [4*lane,4*lane+4).
    u64 hv[8][4];
#pragma unroll
    for (int b = 0; b < 8; ++b) {
      const u64* rp = hprev + (wave * 8 + b) * 256 + 4 * lane;
#pragma unroll
      for (int j = 0; j < 4; ++j) hv[b][j] = ald64(rp + j);
    }
    __builtin_amdgcn_sched_barrier(0);  // sweep issued before MFMA section

    // ---- (3) x-part MFMAs: v = x@Wih^T + bias ----
    f32x4 acc0 = {bv, bv, bv, bv};
    f32x4 acc1 = {bv, bv, bv, bv};
#pragma unroll
    for (int k = 0; k < 16; ++k) {
      int kb = k * 4 + quad;
      int sw = (kb ^ (l15 & 7)) * 8;
      bf16x8 ax0 = *(const bf16x8*)(xcur + l15 * 512 + sw);
      bf16x8 ax1 = *(const bf16x8*)(xcur + (16 + l15) * 512 + sw);
      acc0 = __builtin_amdgcn_mfma_f32_16x16x32_bf16(ax0, wih[k], acc0, 0, 0, 0);
      acc1 = __builtin_amdgcn_mfma_f32_16x16x32_bf16(ax1, wih[k], acc1, 0, 0, 0);
    }
    __builtin_amdgcn_sched_barrier(0);

    // ---- (4) tag check + DENSE batched re-sweeps ----
    {
      const unsigned target = (unsigned)step;
      while (true) {
        int ok = 1;
#pragma unroll
        for (int b = 0; b < 8; ++b)
#pragma unroll
          for (int j = 0; j < 4; ++j)
            ok &= (int)((unsigned)(hv[b][j] >> 32) >= target);
        if (__all(ok)) break;
        __builtin_amdgcn_s_sleep(1);
#pragma unroll
        for (int b = 0; b < 8; ++b) {
          const u64* rp = hprev + (wave * 8 + b) * 256 + 4 * lane;
#pragma unroll
          for (int j = 0; j < 4; ++j) hv[b][j] = ald64(rp + j);
        }
      }
    }

    // ---- (5) stage payloads -> swizzled hA (one b128 per batch; hv dies) ----
#pragma unroll
    for (int b = 0; b < 8; ++b) {
      int m = wave * 8 + b;
      u32x4 blk = {(unsigned)hv[b][0], (unsigned)hv[b][1],
                   (unsigned)hv[b][2], (unsigned)hv[b][3]};
      *(u32x4*)(hA + m * 512 + ((lane ^ (m & 7)) * 8)) = blk;
    }

    // ---- (6) x(t+2) prefetch: issued post-detect, ~2us of slack ahead ----
    if (step < 510) {
#pragma unroll
      for (int i = 0; i < 8; ++i) {
        int c = i * 256 + tid;
        int m = c >> 6, kbp = c & 63;
        int kb = kbp ^ (m & 7);
        int tr = (dir == 0) ? (step + 2) : ((509 - step + lenR[i]) & 511);
        const float4* p = (const float4*)(x + ((size_t)m * 512 + tr) * 512 + kb * 8);
        xp[i][0] = p[0]; xp[i][1] = p[1];
      }
    }
    bar_lgkm();  // C: hA + xnxt visible (loads ride through)

    // ---- (7) h-part MFMAs: v += h@Whh^T ----
#pragma unroll
    for (int k = 0; k < 16; ++k) {
      int kb = k * 4 + quad;
      int sw = (kb ^ (l15 & 7)) * 8;
      bf16x8 ah0 = *(const bf16x8*)(hA + l15 * 512 + sw);
      bf16x8 ah1 = *(const bf16x8*)(hA + (16 + l15) * 512 + sw);
      acc0 = __builtin_amdgcn_mfma_f32_16x16x32_bf16(ah0, whh[k], acc0, 0, 0, 0);
      acc1 = __builtin_amdgcn_mfma_f32_16x16x32_bf16(ah1, whh[k], acc1, 0, 0, 0);
    }
#pragma unroll
    for (int r = 0; r < 4; ++r) {
      vbuf[wave][quad * 4 + r][l15] = acc0[r];
      vbuf[wave][16 + quad * 4 + r][l15] = acc1[r];
    }
    bar_lgkm();  // D: vbuf ready

    // ---- (8) cell update (R9 mapping: cb=tid>>3, cj=(tid&7)*2) ----
    float i0 = vbuf[0][cb][cj],     f0 = vbuf[1][cb][cj];
    float g0 = vbuf[2][cb][cj],     o0 = vbuf[3][cb][cj];
    float i1 = vbuf[0][cb][cj + 1], f1 = vbuf[1][cb][cj + 1];
    float g1 = vbuf[2][cb][cj + 1], o1 = vbuf[3][cb][cj + 1];
    float c0 = sigmoidf_(f0) * creg0 + sigmoidf_(i0) * tanhf_(g0);
    float c1 = sigmoidf_(f1) * creg1 + sigmoidf_(i1) * tanhf_(g1);
    creg0 = c0; creg1 = c1;
    float h0 = tanhf_(c0) * sigmoidf_(o0);
    float h1 = tanhf_(c1) * sigmoidf_(o1);

    // ---- (9) tagged h store: coalesced 64B line per 8 lanes of one wave ----
    unsigned ulo = (unsigned)__builtin_bit_cast(unsigned short, (bf16)h0);
    unsigned uhi = (unsigned)__builtin_bit_cast(unsigned short, (bf16)h1);
    u64 pk = ((u64)(unsigned)(step + 1) << 32) | (u64)(ulo | (uhi << 16));
    ast64(hnext + cb * 256 + s * 8 + (tid & 7), pk);   // fire and forget

    // ---- (10) out store (coalesced 64B per 8-thread group) ----
    int tr = (dir == 0) ? step : ((511 - step + lenO) & 511);
    *(float2*)(out + (size_t)(cb * 512 + tr) * 1024 + dir * 512 + s * 16 + cj) =
        make_float2(h0, h1);
  }
}

extern "C" void kernel_launch(void* const* d_in, const int* in_sizes, int n_in,
                              void* d_out, int out_size, void* d_ws, size_t ws_size,
                              hipStream_t stream) {
  (void)in_sizes; (void)n_in; (void)out_size; (void)ws_size;
  const float* x    = (const float*)d_in[0];
  const int*   mask = (const int*)  d_in[1];
  const float* Wihf = (const float*)d_in[2];
  const float* bihf = (const float*)d_in[3];
  const float* Whhf = (const float*)d_in[4];
  const float* Wihb = (const float*)d_in[5];
  const float* bihb = (const float*)d_in[6];
  const float* Whhb = (const float*)d_in[7];
  float* out = (float*)d_out;

  char* ws = (char*)d_ws;
  u64* hbuf = (u64*)ws;                          // 2*2*32*256*8 = 262144 B
  int* lengths = (int*)(ws + 262144);            // 128 B
  const size_t head = 262144;

  hipMemsetAsync(d_ws, 0, head, stream);  // zero tags + h0 = c0 = 0 every call
  lengths_kernel<<<1, 256, 0, stream>>>(mask, lengths);
  lstm_fused<<<dim3(32, 2), 256, 0, stream>>>(
      x, Wihf, bihf, Whhf, Wihb, bihb, Whhb, lengths, hbuf, out);
}